// Round 10
// baseline (344.984 us; speedup 1.0000x reference)
//
#include <hip/hip_runtime.h>
#include <hip/hip_bf16.h>
#include <math.h>

#define N_NODES 40000
#define N_EDGES 640000
#define D 128
#define N_GRAPHS 128
#define SCAN_NBLK ((N_NODES + 255) / 256)   // 157

typedef __attribute__((ext_vector_type(8))) short bf16x8;
typedef __attribute__((ext_vector_type(4))) float f32x4;
typedef __attribute__((ext_vector_type(2))) float f32x2;
typedef __attribute__((ext_vector_type(4))) unsigned int u32x4;
typedef __attribute__((ext_vector_type(2))) unsigned int u32x2;
typedef unsigned int __attribute__((address_space(3))) lds_u32;
typedef unsigned int __attribute__((address_space(1))) glb_u32;

static __device__ __forceinline__ unsigned short f2b(float f) {
    unsigned int u = __float_as_uint(f);
    unsigned int r = (u + 0x7fffu + ((u >> 16) & 1u)) >> 16;  // RNE
    return (unsigned short)r;
}
// monotonic f32 -> u32 key (unsigned order == float order)
static __device__ __forceinline__ unsigned int fkey(float x) {
    unsigned int b = __float_as_uint(x);
    return (b & 0x80000000u) ? ~b : (b | 0x80000000u);
}
// f32 -> fp8 e4m3 byte (HW cvt)
static __device__ __forceinline__ unsigned int f2p8(float f) {
    return __builtin_amdgcn_cvt_pk_fp8_f32(f, 0.f, 0, false) & 0xffu;
}

// ---- init: zero counts + dummy rows (bf16 + fp8), seed out keys ------------
__global__ void __launch_bounds__(256) k_init(
    int* __restrict__ counts,
    unsigned short* __restrict__ xb, unsigned short* __restrict__ hA,
    unsigned short* __restrict__ hB,
    unsigned char* __restrict__ x8, unsigned char* __restrict__ h8A,
    unsigned char* __restrict__ h8B, unsigned int* __restrict__ outk) {
    int n = blockIdx.x * 256 + threadIdx.x;
    if (n < N_GRAPHS * D) outk[n] = 0x007FFFFFu;   // key(-inf)
    if (n < N_NODES) counts[n] = 0;
    if (blockIdx.x == SCAN_NBLK) {   // block 157: zero the dummy rows
        int t = threadIdx.x;
        u32x4 z = {0u, 0u, 0u, 0u};
        if (t < 48) {          // bf16 rows: 3 x 256B
            int row = t >> 4, c = t & 15;
            unsigned short* p = (row == 0) ? xb : (row == 1) ? hA : hB;
            ((u32x4*)(p + (size_t)N_NODES * D))[c] = z;
        } else if (t < 72) {   // fp8 rows: 3 x 128B
            int row = (t - 48) >> 3, c = (t - 48) & 7;
            unsigned char* p = (row == 0) ? x8 : (row == 1) ? h8A : h8B;
            ((u32x4*)(p + (size_t)N_NODES * D))[c] = z;
        }
    }
}

// ---- packed: hist (2500 blk) + x2b/x2fp8 (2500 blk) + wprep3 (384 blk) -----
__global__ void __launch_bounds__(256) k_pack1(
    const int* __restrict__ ei, int* __restrict__ counts,
    const float* __restrict__ x, unsigned int* __restrict__ xb,
    unsigned char* __restrict__ x8,
    const float* __restrict__ Wr0, const float* __restrict__ Wt0,
    const float* __restrict__ Wr1, const float* __restrict__ Wt1,
    const float* __restrict__ Wr2, const float* __restrict__ Wt2,
    unsigned short* __restrict__ WT) {
    int b = blockIdx.x;
    int t = threadIdx.x;
    if (b < 2500) {
        int e = b * 256 + t;
        atomicAdd(&counts[ei[N_EDGES + e]], 1);
    } else if (b < 5000) {
        int i = (b - 2500) * 256 + t;   // 8 feats per thread
        const f32x4* xv = (const f32x4*)x;
        f32x4 v0 = xv[i * 2], v1 = xv[i * 2 + 1];
        u32x4 o;
        o.x = ((unsigned int)f2b(v0.y) << 16) | f2b(v0.x);
        o.y = ((unsigned int)f2b(v0.w) << 16) | f2b(v0.z);
        o.z = ((unsigned int)f2b(v1.y) << 16) | f2b(v1.x);
        o.w = ((unsigned int)f2b(v1.w) << 16) | f2b(v1.z);
        ((u32x4*)xb)[i] = o;
        // fp8 shadow: byte f = feat f
        unsigned p0 = __builtin_amdgcn_cvt_pk_fp8_f32(v0.x, v0.y, 0, false);
        p0 = __builtin_amdgcn_cvt_pk_fp8_f32(v0.z, v0.w, p0, true);
        unsigned p1 = __builtin_amdgcn_cvt_pk_fp8_f32(v1.x, v1.y, 0, false);
        p1 = __builtin_amdgcn_cvt_pk_fp8_f32(v1.z, v1.w, p1, true);
        u32x2 o8; o8.x = p0; o8.y = p1;
        ((u32x2*)x8)[i] = o8;
    } else {
        int bw = b - 5000;                 // 0..383
        int l = bw >> 7, c = bw & 127, k = t;
        const float* Wrel = (l == 0) ? Wr0 : (l == 1) ? Wr1 : Wr2;
        const float* Wroot = (l == 0) ? Wt0 : (l == 1) ? Wt1 : Wt2;
        float v = (k < D) ? Wrel[k * D + c] : Wroot[(k - D) * D + c];
        WT[(size_t)l * 128 * 256 + c * 256 + k] = f2b(v);
    }
}

// ---- scan of padded (x16) degrees ------------------------------------------
__global__ void __launch_bounds__(256) k_scan1(const int* __restrict__ counts,
                                               int* __restrict__ local_pre,
                                               int* __restrict__ blocksums) {
    int t = threadIdx.x;
    int i = blockIdx.x * 256 + t;
    int lane = t & 63, wave = t >> 6;
    int v = (i < N_NODES) ? ((counts[i] + 15) & ~15) : 0;   // pad degree to x16
    int incl = v;
#pragma unroll
    for (int off = 1; off < 64; off <<= 1) {
        int u = __shfl_up(incl, off);
        if (lane >= off) incl += u;
    }
    __shared__ int ws[4];
    if (lane == 63) ws[wave] = incl;
    __syncthreads();
    int base = 0;
    for (int w = 0; w < 4; ++w) {
        int s = ws[w];
        if (w < wave) base += s;
    }
    if (i < N_NODES) local_pre[i] = base + incl - v;
    if (t == 255) blocksums[blockIdx.x] = base + incl;
}

// Fused scan2+scan3: block reduces blocksums[0..bid), emits row starts +
// cursor + dummy-slot fill (zero-row index N_NODES).
__global__ void __launch_bounds__(256) k_scan3(const int* __restrict__ local_pre,
                                               const int* __restrict__ blocksums,
                                               const int* __restrict__ counts,
                                               int* __restrict__ rp_pad,
                                               int* __restrict__ cursor,
                                               int* __restrict__ src_pad) {
    int t = threadIdx.x;
    int lane = t & 63, wave = t >> 6;
    int bid = blockIdx.x;
    int v = (t < bid) ? blocksums[t] : 0;   // bid <= 156 < 256
#pragma unroll
    for (int off = 32; off >= 1; off >>= 1) v += __shfl_xor(v, off);
    __shared__ int ws[4];
    if (lane == 0) ws[wave] = v;
    __syncthreads();
    int base = ws[0] + ws[1] + ws[2] + ws[3];   // exclusive prefix for this block

    int i = bid * 256 + t;
    if (i < N_NODES) {
        int rp = base + local_pre[i];
        rp_pad[i] = rp;
        cursor[i] = rp;
        int c = counts[i];
        int pc = (c + 15) & ~15;
        for (int j = rp + c; j < rp + pc; ++j) src_pad[j] = N_NODES;
        if (i == N_NODES - 1) rp_pad[N_NODES] = rp + pc;
    }
}

__global__ void k_scatter(const int* __restrict__ ei, int* __restrict__ cursor,
                          int* __restrict__ src_pad) {
    int e = blockIdx.x * blockDim.x + threadIdx.x;
    if (e < N_EDGES) {
        int d = ei[N_EDGES + e];
        int pos = atomicAdd(&cursor[d], 1);
        src_pad[pos] = ei[e];
    }
}

// ---- feature-half gather pass ----------------------------------------------
// R9 post-mortem: gather pinned at ~36us/layer across all structures because
// the 5.1MB fp8 table CANNOT be resident in the 4MB per-XCD L2 (FETCH shows
// 2.7x table re-fetch from HBM; NT hints null - it's a CAPACITY problem).
// Fix: split the gather by FEATURE HALF. Each pass touches a 2.55MB sub-table
// (strided 64B of every 128B row) that FITS per-XCD L2 -> after ~2.55MB/XCD
// warm-up every gather is an L2 hit (~200cy vs ~900cy HBM). Passes must be
// separate DISPATCHES (within one kernel, resident blocks mix passes and the
// union working set is 5.1MB again). Structure per chunk: 16 rows x 64B =
// 1 global_load_lds (lane-linear, 16B/lane), double-buffered, same vmcnt(0)
// dbuf as R3. LDS only 8KB/block -> occupancy cap 44%->100% (8 blk/CU), so
// the short unpack (2 ds_read + 8 cvt + 16 add) hides L2-hit latency via TLP.
// Lane (j8=l>>3, c8=l&7) accumulates feats 8c8..+7 of rows {j8, j8+8};
// shfl_xor(8,16,32) folds; lane<8 stores the 64-feat half row (bf16) to aggG.
template <int HALF>
__global__ void __launch_bounds__(256) k_gather(
    const unsigned char* __restrict__ in8,  // [N+1][128] fp8 (row N zero)
    const int* __restrict__ rp_pad,
    const int* __restrict__ src_pad,
    unsigned short* __restrict__ aggG) {    // [N][128] bf16 (our half cols)
    __shared__ __align__(1024) char stage[4][2][1024];   // [wave][buf][chunk]

    int tid = threadIdx.x;
    int w = tid >> 6;
    int lane = tid & 63;
    int nodebase = blockIdx.x * 16;

    const int* rp = rp_pad + nodebase + w * 4;
    int r0 = rp[0], r1 = rp[1], r2 = rp[2], r3 = rp[3], r4 = rp[4];

    int j16 = lane >> 2;                          // staging row 0..15
    unsigned q16 = (unsigned)(lane & 3) * 16u;    // 16B quarter of 64B half-row
    int j8 = lane >> 3;                           // unpack row subgroup 0..7
    int c8 = lane & 7;                            // feat chunk: feats 8c8..+7
    const char* in8b = (const char*)in8;

    float a0 = 0.f, a1 = 0.f, a2 = 0.f, a3 = 0.f;
    float a4 = 0.f, a5 = 0.f, a6 = 0.f, a7 = 0.f;

#define STAGE1(BI, IA)                                                         \
    __builtin_amdgcn_global_load_lds(                                          \
        (const glb_u32*)(in8b + (((size_t)(unsigned)(IA)) << 7) +              \
                         (HALF ? 64u : 0u) + q16),                             \
        (lds_u32*)&stage[w][BI][0], 16, 0, 0)

    auto acc2 = [&](u32x2 dv) {
        f32x2 p;
        p = __builtin_amdgcn_cvt_pk_f32_fp8(dv.x, false); a0 += p.x; a1 += p.y;
        p = __builtin_amdgcn_cvt_pk_f32_fp8(dv.x, true);  a2 += p.x; a3 += p.y;
        p = __builtin_amdgcn_cvt_pk_f32_fp8(dv.y, false); a4 += p.x; a5 += p.y;
        p = __builtin_amdgcn_cvt_pk_f32_fp8(dv.y, true);  a6 += p.x; a7 += p.y;
    };

    int ia = 0;
    int pos = r0;
    int bi = 0, bc = 0;
    if (pos < r4) {   // prologue: stage chunk 0, prefetch chunk-1 index
        ia = src_pad[pos + j16];
        STAGE1(0, ia);
        bi = 1;
        pos += 16;
        if (pos < r4) ia = src_pad[pos + j16];
    }

#pragma unroll
    for (int n = 0; n < 4; ++n) {
        int ps = (n == 0) ? r0 : (n == 1) ? r1 : (n == 2) ? r2 : r3;
        int pe = (n == 0) ? r1 : (n == 1) ? r2 : (n == 2) ? r3 : r4;
        for (int p = ps; p < pe; p += 16) {
            asm volatile("s_waitcnt vmcnt(0)" ::: "memory");
            if (pos < r4) {              // stage next chunk into other buffer
                STAGE1(bi, ia);
                bi ^= 1;
                pos += 16;
                if (pos < r4) ia = src_pad[pos + j16];
            }
            const char* sb = &stage[w][bc][0];
            u32x2 d0 = *(const u32x2*)(sb + j8 * 64 + c8 * 8);         // row j8
            u32x2 d1 = *(const u32x2*)(sb + (j8 + 8) * 64 + c8 * 8);   // row j8+8
            acc2(d0);
            acc2(d1);
            bc ^= 1;
        }
        // fold the 8 row subgroups, store half-row bf16, reset accumulators
#define RZ(a) { a += __shfl_xor(a, 8); a += __shfl_xor(a, 16); a += __shfl_xor(a, 32); }
        RZ(a0) RZ(a1) RZ(a2) RZ(a3) RZ(a4) RZ(a5) RZ(a6) RZ(a7)
#undef RZ
        if (lane < 8) {   // lane c8 holds feats 8c8..8c8+7 of this half
            u32x4 o;
            o.x = ((unsigned int)f2b(a1) << 16) | f2b(a0);
            o.y = ((unsigned int)f2b(a3) << 16) | f2b(a2);
            o.z = ((unsigned int)f2b(a5) << 16) | f2b(a4);
            o.w = ((unsigned int)f2b(a7) << 16) | f2b(a6);
            *(u32x4*)(aggG + (size_t)(nodebase + w * 4 + n) * D +
                      (HALF ? 64 : 0) + c8 * 8) = o;
        }
        a0 = a1 = a2 = a3 = 0.f;
        a4 = a5 = a6 = a7 = 0.f;
    }
#undef STAGE1
}

// ---- GEMM + epilogue: out[16][256] = [aggG|X] @ [W_rel;W_root] + b ---------
// Identical math to the old k_layer phase 2; A-operand now read from aggG
// (bf16, written by the two k_gather passes; L2-hot).
__global__ void __launch_bounds__(256) k_gemm(
    const unsigned short* __restrict__ in,    // [N+1][128] bf16 X
    const unsigned short* __restrict__ aggG,  // [N][128] bf16 agg
    const unsigned short* __restrict__ WT,    // [128][256] bf16 (k contiguous)
    const float* __restrict__ bias,
    unsigned short* __restrict__ out,         // bf16 out (unused if outk)
    unsigned char* __restrict__ out8,         // fp8 out  (unused if outk)
    const int* __restrict__ batch,
    unsigned int* __restrict__ outk) {        // null for layers 0,1
    __shared__ unsigned char agg8[16 * 128];  // fp8-shadow transpose buffer

    int tid = threadIdx.x;
    int w = tid >> 6;
    int lane = tid & 63;
    int nodebase = blockIdx.x * 16;
    int row = lane & 15, quad = lane >> 4;
    int colbase = w * 32;

    f32x4 gacc0 = {0.f, 0.f, 0.f, 0.f};
    f32x4 gacc1 = {0.f, 0.f, 0.f, 0.f};

    const short* Ap = (const short*)(aggG + (size_t)(nodebase + row) * D);
    const short* Xp = (const short*)(in + (size_t)(nodebase + row) * D);
    const short* W0 = (const short*)(WT + (colbase + row) * 256);
    const short* W1 = (const short*)(WT + (colbase + 16 + row) * 256);

#pragma unroll
    for (int t = 0; t < 4; ++t) {
        int k0 = t * 32 + quad * 8;
        bf16x8 af = *(const bf16x8*)(Ap + k0);
        bf16x8 b0 = *(const bf16x8*)(W0 + k0);
        bf16x8 b1 = *(const bf16x8*)(W1 + k0);
        gacc0 = __builtin_amdgcn_mfma_f32_16x16x32_bf16(af, b0, gacc0, 0, 0, 0);
        gacc1 = __builtin_amdgcn_mfma_f32_16x16x32_bf16(af, b1, gacc1, 0, 0, 0);
    }
#pragma unroll
    for (int t = 0; t < 4; ++t) {
        int k0 = t * 32 + quad * 8;
        bf16x8 xf = *(const bf16x8*)(Xp + k0);
        bf16x8 b0 = *(const bf16x8*)(W0 + 128 + k0);
        bf16x8 b1 = *(const bf16x8*)(W1 + 128 + k0);
        gacc0 = __builtin_amdgcn_mfma_f32_16x16x32_bf16(xf, b0, gacc0, 0, 0, 0);
        gacc1 = __builtin_amdgcn_mfma_f32_16x16x32_bf16(xf, b1, gacc1, 0, 0, 0);
    }

    int c0 = colbase + row, c1 = c0 + 16;
    float bia0 = bias[c0], bia1 = bias[c1];
    float v0[4], v1[4];
#pragma unroll
    for (int r = 0; r < 4; ++r) { v0[r] = gacc0[r] + bia0; v1[r] = gacc1[r] + bia1; }

    if (outk == nullptr) {
        // layers 0,1: relu + bf16 store + fp8 shadow store
#pragma unroll
        for (int r = 0; r < 4; ++r) {
            int n2 = nodebase + quad * 4 + r;
            float r0v = fmaxf(v0[r], 0.f), r1v = fmaxf(v1[r], 0.f);
            out[n2 * D + c0] = f2b(r0v);
            out[n2 * D + c1] = f2b(r1v);
            v0[r] = r0v; v1[r] = r1v;
        }
#pragma unroll
        for (int r = 0; r < 4; ++r) {
            int n2l = quad * 4 + r;
            agg8[n2l * 128 + c0] = (unsigned char)f2p8(v0[r]);
            agg8[n2l * 128 + c1] = (unsigned char)f2p8(v1[r]);
        }
        __syncthreads();
        if (tid < 128) {   // 16 rows x 128B = 2KB, 16B per thread
            int nl = tid >> 3, co = (tid & 7) * 16;
            *(u32x4*)(out8 + (size_t)(nodebase + nl) * D + co) =
                *(const u32x4*)(agg8 + nl * 128 + co);
        }
    } else {
        // layer 2: fused global_max_pool (batch sorted)
        int g0 = batch[nodebase];
        int g15 = batch[nodebase + 15];
        if (g0 == g15) {
            float m0 = fmaxf(fmaxf(v0[0], v0[1]), fmaxf(v0[2], v0[3]));
            float m1 = fmaxf(fmaxf(v1[0], v1[1]), fmaxf(v1[2], v1[3]));
            m0 = fmaxf(m0, __shfl_xor(m0, 16)); m0 = fmaxf(m0, __shfl_xor(m0, 32));
            m1 = fmaxf(m1, __shfl_xor(m1, 16)); m1 = fmaxf(m1, __shfl_xor(m1, 32));
            if (quad == 0) {
                atomicMax(&outk[g0 * D + c0], fkey(m0));
                atomicMax(&outk[g0 * D + c1], fkey(m1));
            }
        } else {  // boundary block (~5%): per-value atomics
#pragma unroll
            for (int r = 0; r < 4; ++r) {
                int gg = batch[nodebase + quad * 4 + r];
                atomicMax(&outk[gg * D + c0], fkey(v0[r]));
                atomicMax(&outk[gg * D + c1], fkey(v1[r]));
            }
        }
    }
}

// ---- unmap keys -> floats (in place over d_out) ----------------------------
__global__ void k_unmap(unsigned int* __restrict__ outk) {
    int i = blockIdx.x * 256 + threadIdx.x;   // 64 blocks x 256 = 16384
    unsigned int k = outk[i];
    unsigned int b = (k & 0x80000000u) ? (k ^ 0x80000000u) : ~k;
    ((float*)outk)[i] = __uint_as_float(b);
}

extern "C" void kernel_launch(void* const* d_in, const int* in_sizes, int n_in,
                              void* d_out, int out_size, void* d_ws, size_t ws_size,
                              hipStream_t stream) {
    const float* x = (const float*)d_in[0];
    const int* ei = (const int*)d_in[1];
    const int* batch = (const int*)d_in[2];
    const float* Wrel[3]  = {(const float*)d_in[3], (const float*)d_in[6], (const float*)d_in[9]};
    const float* brel[3]  = {(const float*)d_in[4], (const float*)d_in[7], (const float*)d_in[10]};
    const float* Wroot[3] = {(const float*)d_in[5], (const float*)d_in[8], (const float*)d_in[11]};
    unsigned int* outk = (unsigned int*)d_out;

    char* ws = (char*)d_ws;
    size_t off = 0;
    auto alloc = [&](size_t bytes) -> void* {
        void* p = ws + off;
        off = (off + bytes + 255) & ~(size_t)255;
        return p;
    };
    // activation buffers have one extra zero row (index N_NODES)
    unsigned short* xb  = (unsigned short*)alloc((size_t)(N_NODES + 1) * D * 2);
    unsigned short* hA  = (unsigned short*)alloc((size_t)(N_NODES + 1) * D * 2);
    unsigned short* hB  = (unsigned short*)alloc((size_t)(N_NODES + 1) * D * 2);
    unsigned char* x8   = (unsigned char*)alloc((size_t)(N_NODES + 1) * D);
    unsigned char* h8A  = (unsigned char*)alloc((size_t)(N_NODES + 1) * D);
    unsigned char* h8B  = (unsigned char*)alloc((size_t)(N_NODES + 1) * D);
    unsigned short* aggG = (unsigned short*)alloc((size_t)N_NODES * D * 2);
    unsigned short* WT  = (unsigned short*)alloc((size_t)3 * 128 * 256 * 2);
    int* rp_pad     = (int*)alloc((size_t)(N_NODES + 1) * 4);
    int* counts     = (int*)alloc((size_t)N_NODES * 4);
    int* cursor     = (int*)alloc((size_t)N_NODES * 4);
    int* src_pad    = (int*)alloc((size_t)(N_EDGES + 16 * N_NODES) * 4);
    int* local_pre  = (int*)alloc((size_t)N_NODES * 4);
    int* blocksums  = (int*)alloc((size_t)SCAN_NBLK * 4);

    // init (zero counts + dummy rows + out keys)
    k_init<<<SCAN_NBLK + 1, 256, 0, stream>>>(counts, xb, hA, hB, x8, h8A, h8B, outk);
    // packed: hist + x2b/x2fp8 + wprep3
    k_pack1<<<5384, 256, 0, stream>>>(ei, counts, x, (unsigned int*)xb, x8,
                                      Wrel[0], Wroot[0], Wrel[1], Wroot[1],
                                      Wrel[2], Wroot[2], WT);
    // scan (padded degrees) + dummy fill + scatter
    k_scan1<<<SCAN_NBLK, 256, 0, stream>>>(counts, local_pre, blocksums);
    k_scan3<<<SCAN_NBLK, 256, 0, stream>>>(local_pre, blocksums, counts,
                                           rp_pad, cursor, src_pad);
    k_scatter<<<(N_EDGES + 255) / 256, 256, 0, stream>>>(ei, cursor, src_pad);

    // 3 layers: two feature-half gather passes (each half-table L2-resident)
    // + GEMM/epilogue. Layer 2's k_gemm folds the global max pool.
    const unsigned char* in8s[3] = {x8, h8A, h8B};
    const unsigned short* ins[3] = {xb, hA, hB};
    unsigned short* outs[3] = {hA, hB, nullptr};
    unsigned char* out8s[3] = {h8A, h8B, nullptr};
    for (int l = 0; l < 3; ++l) {
        k_gather<0><<<N_NODES / 16, 256, 0, stream>>>(in8s[l], rp_pad, src_pad, aggG);
        k_gather<1><<<N_NODES / 16, 256, 0, stream>>>(in8s[l], rp_pad, src_pad, aggG);
        k_gemm<<<N_NODES / 16, 256, 0, stream>>>(ins[l], aggG, WT + l * 128 * 256,
                                                 brel[l], outs[l], out8s[l], batch,
                                                 (l == 2) ? outk : nullptr);
    }

    // keys -> floats
    k_unmap<<<N_GRAPHS * D / 256, 256, 0, stream>>>(outk);
}

// Round 11
// 265.081 us; speedup vs baseline: 1.3014x; 1.3014x over previous
//
#include <hip/hip_runtime.h>
#include <hip/hip_bf16.h>
#include <math.h>

#define N_NODES 40000
#define N_EDGES 640000
#define D 128
#define N_GRAPHS 128
#define SCAN_NBLK ((N_NODES + 255) / 256)   // 157
#define LDS_STRIDE 68                        // words per agg row (pad vs 64 to spread banks)

typedef __attribute__((ext_vector_type(8))) short bf16x8;
typedef __attribute__((ext_vector_type(4))) float f32x4;
typedef __attribute__((ext_vector_type(2))) float f32x2;
typedef __attribute__((ext_vector_type(4))) unsigned int u32x4;
typedef __attribute__((ext_vector_type(2))) unsigned int u32x2;
typedef unsigned int __attribute__((address_space(3))) lds_u32;
typedef unsigned int __attribute__((address_space(1))) glb_u32;

static __device__ __forceinline__ unsigned short f2b(float f) {
    unsigned int u = __float_as_uint(f);
    unsigned int r = (u + 0x7fffu + ((u >> 16) & 1u)) >> 16;  // RNE
    return (unsigned short)r;
}
// monotonic f32 -> u32 key (unsigned order == float order)
static __device__ __forceinline__ unsigned int fkey(float x) {
    unsigned int b = __float_as_uint(x);
    return (b & 0x80000000u) ? ~b : (b | 0x80000000u);
}
// f32 -> fp8 e4m3 byte (HW cvt)
static __device__ __forceinline__ unsigned int f2p8(float f) {
    return __builtin_amdgcn_cvt_pk_fp8_f32(f, 0.f, 0, false) & 0xffu;
}

// ---- init: zero counts + dummy rows (bf16 + fp8), seed out keys ------------
__global__ void __launch_bounds__(256) k_init(
    int* __restrict__ counts,
    unsigned short* __restrict__ xb, unsigned short* __restrict__ hA,
    unsigned short* __restrict__ hB,
    unsigned char* __restrict__ x8, unsigned char* __restrict__ h8A,
    unsigned char* __restrict__ h8B, unsigned int* __restrict__ outk) {
    int n = blockIdx.x * 256 + threadIdx.x;
    if (n < N_GRAPHS * D) outk[n] = 0x007FFFFFu;   // key(-inf)
    if (n < N_NODES) counts[n] = 0;
    if (blockIdx.x == SCAN_NBLK) {   // block 157: zero the dummy rows
        int t = threadIdx.x;
        u32x4 z = {0u, 0u, 0u, 0u};
        if (t < 48) {          // bf16 rows: 3 x 256B
            int row = t >> 4, c = t & 15;
            unsigned short* p = (row == 0) ? xb : (row == 1) ? hA : hB;
            ((u32x4*)(p + (size_t)N_NODES * D))[c] = z;
        } else if (t < 72) {   // fp8 rows: 3 x 128B
            int row = (t - 48) >> 3, c = (t - 48) & 7;
            unsigned char* p = (row == 0) ? x8 : (row == 1) ? h8A : h8B;
            ((u32x4*)(p + (size_t)N_NODES * D))[c] = z;
        }
    }
}

// ---- packed: hist (2500 blk) + x2b/x2fp8 (2500 blk) + wprep3 (384 blk) -----
__global__ void __launch_bounds__(256) k_pack1(
    const int* __restrict__ ei, int* __restrict__ counts,
    const float* __restrict__ x, unsigned int* __restrict__ xb,
    unsigned char* __restrict__ x8,
    const float* __restrict__ Wr0, const float* __restrict__ Wt0,
    const float* __restrict__ Wr1, const float* __restrict__ Wt1,
    const float* __restrict__ Wr2, const float* __restrict__ Wt2,
    unsigned short* __restrict__ WT) {
    int b = blockIdx.x;
    int t = threadIdx.x;
    if (b < 2500) {
        int e = b * 256 + t;
        atomicAdd(&counts[ei[N_EDGES + e]], 1);
    } else if (b < 5000) {
        int i = (b - 2500) * 256 + t;   // 8 feats per thread
        const f32x4* xv = (const f32x4*)x;
        f32x4 v0 = xv[i * 2], v1 = xv[i * 2 + 1];
        u32x4 o;
        o.x = ((unsigned int)f2b(v0.y) << 16) | f2b(v0.x);
        o.y = ((unsigned int)f2b(v0.w) << 16) | f2b(v0.z);
        o.z = ((unsigned int)f2b(v1.y) << 16) | f2b(v1.x);
        o.w = ((unsigned int)f2b(v1.w) << 16) | f2b(v1.z);
        ((u32x4*)xb)[i] = o;
        // fp8 shadow: byte f = feat f
        unsigned p0 = __builtin_amdgcn_cvt_pk_fp8_f32(v0.x, v0.y, 0, false);
        p0 = __builtin_amdgcn_cvt_pk_fp8_f32(v0.z, v0.w, p0, true);
        unsigned p1 = __builtin_amdgcn_cvt_pk_fp8_f32(v1.x, v1.y, 0, false);
        p1 = __builtin_amdgcn_cvt_pk_fp8_f32(v1.z, v1.w, p1, true);
        u32x2 o8; o8.x = p0; o8.y = p1;
        ((u32x2*)x8)[i] = o8;
    } else {
        int bw = b - 5000;                 // 0..383
        int l = bw >> 7, c = bw & 127, k = t;
        const float* Wrel = (l == 0) ? Wr0 : (l == 1) ? Wr1 : Wr2;
        const float* Wroot = (l == 0) ? Wt0 : (l == 1) ? Wt1 : Wt2;
        float v = (k < D) ? Wrel[k * D + c] : Wroot[(k - D) * D + c];
        WT[(size_t)l * 128 * 256 + c * 256 + k] = f2b(v);
    }
}

// ---- scan of padded (x16) degrees ------------------------------------------
__global__ void __launch_bounds__(256) k_scan1(const int* __restrict__ counts,
                                               int* __restrict__ local_pre,
                                               int* __restrict__ blocksums) {
    int t = threadIdx.x;
    int i = blockIdx.x * 256 + t;
    int lane = t & 63, wave = t >> 6;
    int v = (i < N_NODES) ? ((counts[i] + 15) & ~15) : 0;   // pad degree to x16
    int incl = v;
#pragma unroll
    for (int off = 1; off < 64; off <<= 1) {
        int u = __shfl_up(incl, off);
        if (lane >= off) incl += u;
    }
    __shared__ int ws[4];
    if (lane == 63) ws[wave] = incl;
    __syncthreads();
    int base = 0;
    for (int w = 0; w < 4; ++w) {
        int s = ws[w];
        if (w < wave) base += s;
    }
    if (i < N_NODES) local_pre[i] = base + incl - v;
    if (t == 255) blocksums[blockIdx.x] = base + incl;
}

// Fused scan2+scan3: block reduces blocksums[0..bid), emits row starts +
// cursor + dummy-slot fill (zero-row index N_NODES).
__global__ void __launch_bounds__(256) k_scan3(const int* __restrict__ local_pre,
                                               const int* __restrict__ blocksums,
                                               const int* __restrict__ counts,
                                               int* __restrict__ rp_pad,
                                               int* __restrict__ cursor,
                                               int* __restrict__ src_pad) {
    int t = threadIdx.x;
    int lane = t & 63, wave = t >> 6;
    int bid = blockIdx.x;
    int v = (t < bid) ? blocksums[t] : 0;   // bid <= 156 < 256
#pragma unroll
    for (int off = 32; off >= 1; off >>= 1) v += __shfl_xor(v, off);
    __shared__ int ws[4];
    if (lane == 0) ws[wave] = v;
    __syncthreads();
    int base = ws[0] + ws[1] + ws[2] + ws[3];   // exclusive prefix for this block

    int i = bid * 256 + t;
    if (i < N_NODES) {
        int rp = base + local_pre[i];
        rp_pad[i] = rp;
        cursor[i] = rp;
        int c = counts[i];
        int pc = (c + 15) & ~15;
        for (int j = rp + c; j < rp + pc; ++j) src_pad[j] = N_NODES;
        if (i == N_NODES - 1) rp_pad[N_NODES] = rp + pc;
    }
}

__global__ void k_scatter(const int* __restrict__ ei, int* __restrict__ cursor,
                          int* __restrict__ src_pad) {
    int e = blockIdx.x * blockDim.x + threadIdx.x;
    if (e < N_EDGES) {
        int d = ei[N_EDGES + e];
        int pos = atomicAdd(&cursor[d], 1);
        src_pad[pos] = ei[e];
    }
}

// ---- fused layer: fp8 gather-sum (global_load_lds dbuf) + bf16 MFMA GEMM ---
// SESSION-BEST VERIFIED STRUCTURE (R3: 267.2us total, absmax 3.0).
// Campaign conclusion (R0-R10, 8 structural variants): the scattered gather
// is pinned at ~36us/layer by a per-request service floor (~26G slots/s
// chip-wide) invariant to bytes/row (bf16 vs fp8 vs 64B-half), pipeline
// depth (1..4), L1 policy, L2 NT hints, and L2 capacity-fit (feature-split).
// Only address locality breaks it (hot-set probe: 10us) - unavailable for a
// random edge list. Phase 1: per 16-edge chunk, 2x global_load_lds stage
// 16 fp8 rows into a 2KB buffer, double-buffered; lane (hh,cc) accumulates
// feats 8cc..8cc+7 of rows ==hh (mod 4) via HW cvt_pk_f32_fp8; shfl_xor
// folds. Phase 2: GEMM out[16][256] = [aggLDS|X_bf16] @ [W_rel;W_root]+b.
// Epilogue: relu + bf16 + fp8-shadow stores; layer 2 folds global_max_pool.
__global__ void __launch_bounds__(256) k_layer(
    const unsigned short* __restrict__ in,  // [N+1][128] bf16 (row N zero)
    const unsigned char* __restrict__ in8,  // [N+1][128] fp8  (row N zero)
    const int* __restrict__ rp_pad,
    const int* __restrict__ src_pad,
    const unsigned short* __restrict__ WT,  // [128][256] bf16 (k contiguous)
    const float* __restrict__ bias,
    unsigned short* __restrict__ out,       // bf16 out (unused if outk)
    unsigned char* __restrict__ out8,       // fp8 out  (unused if outk)
    const int* __restrict__ batch,
    unsigned int* __restrict__ outk) {      // null for layers 0,1
    __shared__ __align__(1024) char stage[4][2][2048];   // [wave][buf][chunk]
    __shared__ __align__(16) unsigned int aggLDS[16 * LDS_STRIDE];

    int tid = threadIdx.x;
    int w = tid >> 6;
    int lane = tid & 63;
    int nodebase = blockIdx.x * 16;

    // ---- phase 1 ----
    const int* rp = rp_pad + nodebase + w * 4;
    int r0 = rp[0], r1 = rp[1], r2 = rp[2], r3 = rp[3], r4 = rp[4];

    int hh = lane >> 4;                      // row subgroup 0..3
    int cc = lane & 15;                      // feature chunk: feats 8cc..8cc+7
    int j8 = lane >> 3;                      // staging row-within-8 (0..7)
    const char* in8b = (const char*)in8;
    unsigned gofs8 = 16u * (unsigned)(lane & 7);   // byte offset in fp8 row

#define STAGE2(BI, IA, IB) do {                                                \
        __builtin_amdgcn_global_load_lds(                                      \
            (const glb_u32*)(in8b + (((size_t)(unsigned)(IA)) << 7) + gofs8),  \
            (lds_u32*)&stage[w][BI][0], 16, 0, 0);                             \
        __builtin_amdgcn_global_load_lds(                                      \
            (const glb_u32*)(in8b + (((size_t)(unsigned)(IB)) << 7) + gofs8),  \
            (lds_u32*)&stage[w][BI][1024], 16, 0, 0);                          \
    } while (0)

    int ia = 0, ib = 0;                      // row indices for chunk at 'pos'
    int pos = r0;                            // next chunk to stage
    int buf_i = 0, buf_c = 0;
    if (pos < r4) {   // prologue: stage chunk 0, prefetch chunk-1 indices
        ia = src_pad[pos + j8];
        ib = src_pad[pos + 8 + j8];
        STAGE2(0, ia, ib);
        buf_i = 1;
        pos += 16;
        if (pos < r4) {
            ia = src_pad[pos + j8];
            ib = src_pad[pos + 8 + j8];
        }
    }

#pragma unroll
    for (int n = 0; n < 4; ++n) {
        int ps = (n == 0) ? r0 : (n == 1) ? r1 : (n == 2) ? r2 : r3;
        int pe = (n == 0) ? r1 : (n == 1) ? r2 : (n == 2) ? r3 : r4;
        float a0 = 0.f, a1 = 0.f, a2 = 0.f, a3 = 0.f;
        float a4 = 0.f, a5 = 0.f, a6 = 0.f, a7 = 0.f;
        for (int p = ps; p < pe; p += 16) {
            // current chunk's staging (+ prefetched indices) complete here;
            // both were in flight during the previous chunk's unpack.
            asm volatile("s_waitcnt vmcnt(0)" ::: "memory");
            if (pos < r4) {              // stage next chunk into other buffer
                STAGE2(buf_i, ia, ib);
                buf_i ^= 1;
                pos += 16;
                if (pos < r4) {          // prefetch indices for chunk after
                    ia = src_pad[pos + j8];
                    ib = src_pad[pos + 8 + j8];
                }
            }
            const char* sb = &stage[w][buf_c][0];
#pragma unroll
            for (int pp = 0; pp < 4; ++pp) {   // rows 4*pp+hh
                u32x2 dv = *(const u32x2*)(sb + 512 * pp + 128 * hh + 8 * cc);
                f32x2 l0 = __builtin_amdgcn_cvt_pk_f32_fp8(dv.x, false);
                f32x2 h0 = __builtin_amdgcn_cvt_pk_f32_fp8(dv.x, true);
                f32x2 l1 = __builtin_amdgcn_cvt_pk_f32_fp8(dv.y, false);
                f32x2 h1 = __builtin_amdgcn_cvt_pk_f32_fp8(dv.y, true);
                a0 += l0.x; a1 += l0.y; a2 += h0.x; a3 += h0.y;
                a4 += l1.x; a5 += l1.y; a6 += h1.x; a7 += h1.y;
            }
            buf_c ^= 1;
        }
        // fold the 4 row subgroups (lane groups) together
#define RED(a) do { a += __shfl_xor(a, 16); a += __shfl_xor(a, 32); } while (0)
        RED(a0); RED(a1); RED(a2); RED(a3);
        RED(a4); RED(a5); RED(a6); RED(a7);
#undef RED
        if (lane < 16) {   // flush node n: feats 8cc..8cc+7 -> words 4cc..4cc+3
            u32x4 o;
            o.x = ((unsigned int)f2b(a1) << 16) | f2b(a0);
            o.y = ((unsigned int)f2b(a3) << 16) | f2b(a2);
            o.z = ((unsigned int)f2b(a5) << 16) | f2b(a4);
            o.w = ((unsigned int)f2b(a7) << 16) | f2b(a6);
            *(u32x4*)&aggLDS[(w * 4 + n) * LDS_STRIDE + 4 * cc] = o;
        }
    }
#undef STAGE2
    __syncthreads();

    // ---- phase 2: GEMM (bf16) ----
    int row = cc, quad = hh;
    int colbase = w * 32;

    f32x4 gacc0 = {0.f, 0.f, 0.f, 0.f};
    f32x4 gacc1 = {0.f, 0.f, 0.f, 0.f};

    const unsigned int* Al = &aggLDS[row * LDS_STRIDE];
    const short* Xp = (const short*)(in + (nodebase + row) * D);
    const short* W0 = (const short*)(WT + (colbase + row) * 256);
    const short* W1 = (const short*)(WT + (colbase + 16 + row) * 256);

#pragma unroll
    for (int t = 0; t < 4; ++t) {
        bf16x8 af = *(const bf16x8*)(Al + t * 16 + quad * 4);
        int k0 = t * 32 + quad * 8;
        bf16x8 b0 = *(const bf16x8*)(W0 + k0);
        bf16x8 b1 = *(const bf16x8*)(W1 + k0);
        gacc0 = __builtin_amdgcn_mfma_f32_16x16x32_bf16(af, b0, gacc0, 0, 0, 0);
        gacc1 = __builtin_amdgcn_mfma_f32_16x16x32_bf16(af, b1, gacc1, 0, 0, 0);
    }
#pragma unroll
    for (int t = 0; t < 4; ++t) {
        int k0 = t * 32 + quad * 8;
        bf16x8 xf = *(const bf16x8*)(Xp + k0);
        bf16x8 b0 = *(const bf16x8*)(W0 + 128 + k0);
        bf16x8 b1 = *(const bf16x8*)(W1 + 128 + k0);
        gacc0 = __builtin_amdgcn_mfma_f32_16x16x32_bf16(xf, b0, gacc0, 0, 0, 0);
        gacc1 = __builtin_amdgcn_mfma_f32_16x16x32_bf16(xf, b1, gacc1, 0, 0, 0);
    }

    int c0 = colbase + row, c1 = c0 + 16;
    float bia0 = bias[c0], bia1 = bias[c1];
    float v0[4], v1[4];
#pragma unroll
    for (int r = 0; r < 4; ++r) { v0[r] = gacc0[r] + bia0; v1[r] = gacc1[r] + bia1; }

    if (outk == nullptr) {
        // layers 0,1: relu + bf16 store
#pragma unroll
        for (int r = 0; r < 4; ++r) {
            int n2 = nodebase + quad * 4 + r;
            float r0v = fmaxf(v0[r], 0.f), r1v = fmaxf(v1[r], 0.f);
            out[n2 * D + c0] = f2b(r0v);
            out[n2 * D + c1] = f2b(r1v);
            v0[r] = r0v; v1[r] = r1v;
        }
        // fp8 shadow store via LDS transpose (reuse aggLDS as [16][128] bytes)
        __syncthreads();   // all waves done reading aggLDS in phase 2
        unsigned char* agg8 = (unsigned char*)aggLDS;
#pragma unroll
        for (int r = 0; r < 4; ++r) {
            int n2l = quad * 4 + r;
            agg8[n2l * 128 + c0] = (unsigned char)f2p8(v0[r]);
            agg8[n2l * 128 + c1] = (unsigned char)f2p8(v1[r]);
        }
        __syncthreads();
        if (tid < 128) {   // 16 rows x 128B = 2KB, 16B per thread
            int nl = tid >> 3, co = (tid & 7) * 16;
            *(u32x4*)(out8 + (size_t)(nodebase + nl) * D + co) =
                *(const u32x4*)(agg8 + nl * 128 + co);
        }
    } else {
        // layer 2: fused global_max_pool (batch sorted)
        int g0 = batch[nodebase];
        int g15 = batch[nodebase + 15];
        if (g0 == g15) {
            float m0 = fmaxf(fmaxf(v0[0], v0[1]), fmaxf(v0[2], v0[3]));
            float m1 = fmaxf(fmaxf(v1[0], v1[1]), fmaxf(v1[2], v1[3]));
            m0 = fmaxf(m0, __shfl_xor(m0, 16)); m0 = fmaxf(m0, __shfl_xor(m0, 32));
            m1 = fmaxf(m1, __shfl_xor(m1, 16)); m1 = fmaxf(m1, __shfl_xor(m1, 32));
            if (quad == 0) {
                atomicMax(&outk[g0 * D + c0], fkey(m0));
                atomicMax(&outk[g0 * D + c1], fkey(m1));
            }
        } else {  // boundary block (~5%): per-value atomics
#pragma unroll
            for (int r = 0; r < 4; ++r) {
                int gg = batch[nodebase + quad * 4 + r];
                atomicMax(&outk[gg * D + c0], fkey(v0[r]));
                atomicMax(&outk[gg * D + c1], fkey(v1[r]));
            }
        }
    }
}

// ---- unmap keys -> floats (in place over d_out) ----------------------------
__global__ void k_unmap(unsigned int* __restrict__ outk) {
    int i = blockIdx.x * 256 + threadIdx.x;   // 64 blocks x 256 = 16384
    unsigned int k = outk[i];
    unsigned int b = (k & 0x80000000u) ? (k ^ 0x80000000u) : ~k;
    ((float*)outk)[i] = __uint_as_float(b);
}

extern "C" void kernel_launch(void* const* d_in, const int* in_sizes, int n_in,
                              void* d_out, int out_size, void* d_ws, size_t ws_size,
                              hipStream_t stream) {
    const float* x = (const float*)d_in[0];
    const int* ei = (const int*)d_in[1];
    const int* batch = (const int*)d_in[2];
    const float* Wrel[3]  = {(const float*)d_in[3], (const float*)d_in[6], (const float*)d_in[9]};
    const float* brel[3]  = {(const float*)d_in[4], (const float*)d_in[7], (const float*)d_in[10]};
    const float* Wroot[3] = {(const float*)d_in[5], (const float*)d_in[8], (const float*)d_in[11]};
    unsigned int* outk = (unsigned int*)d_out;

    char* ws = (char*)d_ws;
    size_t off = 0;
    auto alloc = [&](size_t bytes) -> void* {
        void* p = ws + off;
        off = (off + bytes + 255) & ~(size_t)255;
        return p;
    };
    // activation buffers have one extra zero row (index N_NODES)
    unsigned short* xb  = (unsigned short*)alloc((size_t)(N_NODES + 1) * D * 2);
    unsigned short* hA  = (unsigned short*)alloc((size_t)(N_NODES + 1) * D * 2);
    unsigned short* hB  = (unsigned short*)alloc((size_t)(N_NODES + 1) * D * 2);
    unsigned char* x8   = (unsigned char*)alloc((size_t)(N_NODES + 1) * D);
    unsigned char* h8A  = (unsigned char*)alloc((size_t)(N_NODES + 1) * D);
    unsigned char* h8B  = (unsigned char*)alloc((size_t)(N_NODES + 1) * D);
    unsigned short* WT  = (unsigned short*)alloc((size_t)3 * 128 * 256 * 2);
    int* rp_pad     = (int*)alloc((size_t)(N_NODES + 1) * 4);
    int* counts     = (int*)alloc((size_t)N_NODES * 4);
    int* cursor     = (int*)alloc((size_t)N_NODES * 4);
    int* src_pad    = (int*)alloc((size_t)(N_EDGES + 16 * N_NODES) * 4);
    int* local_pre  = (int*)alloc((size_t)N_NODES * 4);
    int* blocksums  = (int*)alloc((size_t)SCAN_NBLK * 4);

    // init (zero counts + dummy rows + out keys)
    k_init<<<SCAN_NBLK + 1, 256, 0, stream>>>(counts, xb, hA, hB, x8, h8A, h8B, outk);
    // packed: hist + x2b/x2fp8 + wprep3
    k_pack1<<<5384, 256, 0, stream>>>(ei, counts, x, (unsigned int*)xb, x8,
                                      Wrel[0], Wroot[0], Wrel[1], Wroot[1],
                                      Wrel[2], Wroot[2], WT);
    // scan (padded degrees) + dummy fill + scatter
    k_scan1<<<SCAN_NBLK, 256, 0, stream>>>(counts, local_pre, blocksums);
    k_scan3<<<SCAN_NBLK, 256, 0, stream>>>(local_pre, blocksums, counts,
                                           rp_pad, cursor, src_pad);
    k_scatter<<<(N_EDGES + 255) / 256, 256, 0, stream>>>(ei, cursor, src_pad);

    // 3 fused GraphConv layers; layer 2 folds the global max pool
    k_layer<<<N_NODES / 16, 256, 0, stream>>>(xb, x8, rp_pad, src_pad, WT,
                                              brel[0], hA, h8A, batch, nullptr);
    k_layer<<<N_NODES / 16, 256, 0, stream>>>(hA, h8A, rp_pad, src_pad, WT + 128 * 256,
                                              brel[1], hB, h8B, batch, nullptr);
    k_layer<<<N_NODES / 16, 256, 0, stream>>>(hB, h8B, rp_pad, src_pad, WT + 2 * 128 * 256,
                                              brel[2], hB, h8B, batch, outk);

    // keys -> floats
    k_unmap<<<N_GRAPHS * D / 256, 256, 0, stream>>>(outk);
}